// Round 1
// baseline (3162.834 us; speedup 1.0000x reference)
//
#include <hip/hip_runtime.h>

#define D 128

// ---------- CSR build ----------
__global__ void k_hist(const int* __restrict__ dst, int* __restrict__ counts, int E){
  int e = blockIdx.x*256 + threadIdx.x;
  if (e < E) atomicAdd(&counts[dst[e]], 1);
}

__global__ void k_scan1(const int* __restrict__ counts, int* __restrict__ partials, int N){
  __shared__ int sd[256];
  int t = threadIdx.x;
  int base = blockIdx.x*1024 + t*4;
  int s = 0;
  #pragma unroll
  for (int j=0;j<4;j++){ int i=base+j; s += (i<N)?counts[i]:0; }
  sd[t]=s; __syncthreads();
  for (int off=128; off>0; off>>=1){ if (t<off) sd[t]+=sd[t+off]; __syncthreads(); }
  if (t==0) partials[blockIdx.x]=sd[0];
}

__global__ void k_scan2(int* __restrict__ partials, int* __restrict__ row_ptr, int nb, int N){
  if (blockIdx.x==0 && threadIdx.x==0){
    int run=0;
    for (int b=0;b<nb;b++){ int v=partials[b]; partials[b]=run; run+=v; }
    row_ptr[N]=run;
  }
}

__global__ void k_scan3(const int* __restrict__ counts, const int* __restrict__ partials,
                        int* __restrict__ row_ptr, int* __restrict__ cursor, int N){
  __shared__ int sd[256];
  int t=threadIdx.x;
  int base = blockIdx.x*1024 + t*4;
  int v[4]; int s=0;
  #pragma unroll
  for (int j=0;j<4;j++){ int i=base+j; v[j]=(i<N)?counts[i]:0; s+=v[j]; }
  sd[t]=s; __syncthreads();
  for (int off=1; off<256; off<<=1){
    int x = (t>=off)? sd[t-off] : 0;
    __syncthreads();
    sd[t] += x;
    __syncthreads();
  }
  int run = sd[t]-s + partials[blockIdx.x];   // exclusive offset for this thread
  #pragma unroll
  for (int j=0;j<4;j++){ int i=base+j; if (i<N){ row_ptr[i]=run; cursor[i]=run; } run+=v[j]; }
}

__global__ void k_scatter(const int* __restrict__ src, const int* __restrict__ dst,
                          int* __restrict__ cursor, int* __restrict__ elist,
                          int* __restrict__ slist, int E){
  int e = blockIdx.x*256+threadIdx.x;
  if (e<E){
    int d = dst[e];
    int p = atomicAdd(&cursor[d],1);
    elist[p]=e; slist[p]=src[e];
  }
}

// ---------- W_comb = W_an * W_msg ; Mfull = [W_ah | W_comb] ; Wb = W_an * b_m ----------
__global__ void k_comb(const float* __restrict__ Wa, const float* __restrict__ Wm,
                       const float* __restrict__ bm, float* __restrict__ Mfull,
                       float* __restrict__ Wb){
  int o = blockIdx.x; int t = threadIdx.x;
  if (t < 128){
    Mfull[o*384+t] = Wa[o*256+t];
  } else {
    int i = t-128;
    float s=0.f;
    #pragma unroll 4
    for (int p=0;p<128;p++) s += Wa[o*256+128+p]*Wm[p*256+i];
    Mfull[o*384+t] = s;
  }
  if (t==0){
    float s=0.f;
    for (int p=0;p<128;p++) s += Wa[o*256+128+p]*bm[p];
    Wb[o]=s;
  }
}

// ---------- per-node aggregation: S[n] = [sum h_src ; sum e] * 1/max(deg,1) ----------
__global__ void k_agg(const float* __restrict__ nf, const float* __restrict__ ef,
                      const int* __restrict__ rp, const int* __restrict__ elist,
                      const int* __restrict__ slist, float* __restrict__ S, int N){
  int n = blockIdx.x*4 + (threadIdx.x>>6);
  int lane = threadIdx.x & 63;
  if (n>=N) return;
  int r0 = rp[n], r1 = rp[n+1];
  float dinv = 1.0f/fmaxf((float)(r1-r0),1.0f);
  float aH0=0.f,aH1=0.f,aE0=0.f,aE1=0.f;
  for (int j=r0;j<r1;j++){
    int e=elist[j], s=slist[j];
    float2 h2 = reinterpret_cast<const float2*>(nf + (size_t)s*D)[lane];
    float2 e2 = reinterpret_cast<const float2*>(ef + (size_t)e*D)[lane];
    aH0+=h2.x; aH1+=h2.y; aE0+=e2.x; aE1+=e2.y;
  }
  float2* So = reinterpret_cast<float2*>(S + (size_t)n*256);
  So[lane]    = make_float2(aH0*dinv, aH1*dinv);
  So[64+lane] = make_float2(aE0*dinv, aE1*dinv);
}

// ---------- new_h = relu([nf|S] * Mfull^T + b_a + flag*Wb) ----------
// block: 256 thr (16x16), tile 128 nodes x 128 outs, 8x8 acc/thread, K=384 in chunks of 32.
__global__ __launch_bounds__(256, 2) void k_gemm(
    const float* __restrict__ nf, const float* __restrict__ S,
    const float* __restrict__ Mfull, const float* __restrict__ ba,
    const float* __restrict__ Wb, const int* __restrict__ rp,
    float* __restrict__ outH, int N)
{
  __shared__ float Xs[128*32];
  __shared__ float Ms[128*32];
  int tid = threadIdx.x;
  int tx = tid & 15, ty = tid >> 4;
  int bn = blockIdx.x * 128;

  float acc[8][8];
  #pragma unroll
  for (int i=0;i<8;i++)
    #pragma unroll
    for (int j=0;j<8;j++) acc[i][j]=0.f;

  int lrow = tid >> 3;          // 0..31
  int lc   = (tid & 7) << 2;    // 0,4,...,28

  for (int kb = 0; kb < 384; kb += 32){
    __syncthreads();
    #pragma unroll
    for (int pass=0; pass<4; pass++){
      int row = lrow + pass*32;
      int phys = lc ^ (((row>>2)&7)<<2);     // XOR swizzle, 16B-aligned
      int n = bn + row; int nn = (n<N)? n : 0;
      const float* xsrc = (kb < 128) ? (nf + (size_t)nn*128 + kb + lc)
                                     : (S  + (size_t)nn*256 + (kb-128) + lc);
      float4 xv = *reinterpret_cast<const float4*>(xsrc);
      *reinterpret_cast<float4*>(&Xs[row*32 + phys]) = xv;
      float4 mv = *reinterpret_cast<const float4*>(Mfull + (size_t)row*384 + kb + lc);
      *reinterpret_cast<float4*>(&Ms[row*32 + phys]) = mv;
    }
    __syncthreads();
    #pragma unroll
    for (int kk=0; kk<32; kk+=4){
      int px = kk ^ ((tx&7)<<2);
      int pm = kk ^ ((ty&7)<<2);
      float4 xv[8], mv[8];
      #pragma unroll
      for (int i=0;i<4;i++){
        xv[i]   = *reinterpret_cast<const float4*>(&Xs[(4*tx+i)*32    + px]);
        xv[i+4] = *reinterpret_cast<const float4*>(&Xs[(64+4*tx+i)*32 + px]);
        mv[i]   = *reinterpret_cast<const float4*>(&Ms[(4*ty+i)*32    + pm]);
        mv[i+4] = *reinterpret_cast<const float4*>(&Ms[(64+4*ty+i)*32 + pm]);
      }
      #pragma unroll
      for (int i=0;i<8;i++)
        #pragma unroll
        for (int j=0;j<8;j++)
          acc[i][j] += xv[i].x*mv[j].x + xv[i].y*mv[j].y + xv[i].z*mv[j].z + xv[i].w*mv[j].w;
    }
  }

  float4 ba_a = *reinterpret_cast<const float4*>(ba + 4*ty);
  float4 ba_b = *reinterpret_cast<const float4*>(ba + 64 + 4*ty);
  float4 wb_a = *reinterpret_cast<const float4*>(Wb + 4*ty);
  float4 wb_b = *reinterpret_cast<const float4*>(Wb + 64 + 4*ty);
  #pragma unroll
  for (int i=0;i<8;i++){
    int n = (i<4) ? (bn + 4*tx + i) : (bn + 64 + 4*tx + (i-4));
    if (n < N){
      float flag = (rp[n+1]-rp[n] > 0) ? 1.0f : 0.0f;
      float4 o1, o2;
      o1.x = fmaxf(acc[i][0] + ba_a.x + flag*wb_a.x, 0.f);
      o1.y = fmaxf(acc[i][1] + ba_a.y + flag*wb_a.y, 0.f);
      o1.z = fmaxf(acc[i][2] + ba_a.z + flag*wb_a.z, 0.f);
      o1.w = fmaxf(acc[i][3] + ba_a.w + flag*wb_a.w, 0.f);
      o2.x = fmaxf(acc[i][4] + ba_b.x + flag*wb_b.x, 0.f);
      o2.y = fmaxf(acc[i][5] + ba_b.y + flag*wb_b.y, 0.f);
      o2.z = fmaxf(acc[i][6] + ba_b.z + flag*wb_b.z, 0.f);
      o2.w = fmaxf(acc[i][7] + ba_b.w + flag*wb_b.w, 0.f);
      *reinterpret_cast<float4*>(outH + (size_t)n*128 + 4*ty)      = o1;
      *reinterpret_cast<float4*>(outH + (size_t)n*128 + 64 + 4*ty) = o2;
    }
  }
}

// ---------- new_e = 0.5*(new_h[src] + new_h[dst]) ----------
__global__ void k_edge(const int* __restrict__ src, const int* __restrict__ dst,
                       const float* __restrict__ H, float* __restrict__ NE, int E){
  int t = threadIdx.x;
  int e = blockIdx.x*8 + (t>>5);
  if (e>=E) return;
  int l = t & 31;
  const float4* Hs = reinterpret_cast<const float4*>(H + (size_t)src[e]*D);
  const float4* Hd = reinterpret_cast<const float4*>(H + (size_t)dst[e]*D);
  float4 a = Hs[l], b = Hd[l];
  float4 r;
  r.x = 0.5f*(a.x+b.x); r.y = 0.5f*(a.y+b.y);
  r.z = 0.5f*(a.z+b.z); r.w = 0.5f*(a.w+b.w);
  reinterpret_cast<float4*>(NE + (size_t)e*D)[l] = r;
}

extern "C" void kernel_launch(void* const* d_in, const int* in_sizes, int n_in,
                              void* d_out, int out_size, void* d_ws, size_t ws_size,
                              hipStream_t stream)
{
  const float* nf  = (const float*)d_in[0];
  const float* ef  = (const float*)d_in[1];
  const int*   src = (const int*)d_in[2];
  const int*   dst = (const int*)d_in[3];
  const float* Wm  = (const float*)d_in[4];
  const float* bm  = (const float*)d_in[5];
  const float* Wa  = (const float*)d_in[6];
  const float* bap = (const float*)d_in[7];
  int N = in_sizes[0]/D;
  int E = in_sizes[2];
  float* outH = (float*)d_out;
  float* outE = (float*)d_out + (size_t)N*D;

  // carve workspace (falls back to the new_e region of d_out, overwritten last)
  size_t off = 0;
  auto alloc = [&](size_t bytes){ size_t o = off; off = (off + bytes + 255) & ~(size_t)255; return o; };
  size_t o_counts = alloc((size_t)N*4);
  size_t o_rp     = alloc((size_t)(N+1)*4);
  size_t o_part   = alloc(1024*4);
  size_t o_cur    = alloc((size_t)N*4);
  size_t o_el     = alloc((size_t)E*4);
  size_t o_sl     = alloc((size_t)E*4);
  size_t o_M      = alloc((size_t)128*384*4);
  size_t o_wb     = alloc(128*4);
  size_t o_S      = alloc((size_t)N*256*4);
  size_t need = off;
  char* base = (ws_size >= need) ? (char*)d_ws : (char*)(void*)outE;

  int* counts  = (int*)(base + o_counts);
  int* row_ptr = (int*)(base + o_rp);
  int* partials= (int*)(base + o_part);
  int* cursor  = (int*)(base + o_cur);
  int* elist   = (int*)(base + o_el);
  int* slist   = (int*)(base + o_sl);
  float* Mfull = (float*)(base + o_M);
  float* Wb    = (float*)(base + o_wb);
  float* S     = (float*)(base + o_S);

  hipMemsetAsync(counts, 0, (size_t)N*4, stream);

  int NB = (N + 1023)/1024;
  k_hist   <<<(E+255)/256, 256, 0, stream>>>(dst, counts, E);
  k_scan1  <<<NB, 256, 0, stream>>>(counts, partials, N);
  k_scan2  <<<1, 64, 0, stream>>>(partials, row_ptr, NB, N);
  k_scan3  <<<NB, 256, 0, stream>>>(counts, partials, row_ptr, cursor, N);
  k_scatter<<<(E+255)/256, 256, 0, stream>>>(src, dst, cursor, elist, slist, E);
  k_comb   <<<128, 384, 0, stream>>>(Wa, Wm, bm, Mfull, Wb);
  k_agg    <<<(N+3)/4, 256, 0, stream>>>(nf, ef, row_ptr, elist, slist, S, N);
  k_gemm   <<<(N+127)/128, 256, 0, stream>>>(nf, S, Mfull, bap, Wb, row_ptr, outH, N);
  k_edge   <<<(E+7)/8, 256, 0, stream>>>(src, dst, outH, outE, E);
}

// Round 2
// 623.908 us; speedup vs baseline: 5.0694x; 5.0694x over previous
//
#include <hip/hip_runtime.h>

#define D 128

// ---------- CSR build ----------
__global__ void k_hist(const int* __restrict__ dst, int* __restrict__ counts, int E){
  int e = blockIdx.x*256 + threadIdx.x;
  if (e < E) atomicAdd(&counts[dst[e]], 1);
}

__global__ void k_scan1(const int* __restrict__ counts, int* __restrict__ partials, int N){
  __shared__ int sd[256];
  int t = threadIdx.x;
  int base = blockIdx.x*1024 + t*4;
  int s = 0;
  #pragma unroll
  for (int j=0;j<4;j++){ int i=base+j; s += (i<N)?counts[i]:0; }
  sd[t]=s; __syncthreads();
  for (int off=128; off>0; off>>=1){ if (t<off) sd[t]+=sd[t+off]; __syncthreads(); }
  if (t==0) partials[blockIdx.x]=sd[0];
}

__global__ void k_scan2(int* __restrict__ partials, int* __restrict__ row_ptr, int nb, int N){
  if (blockIdx.x==0 && threadIdx.x==0){
    int run=0;
    for (int b=0;b<nb;b++){ int v=partials[b]; partials[b]=run; run+=v; }
    row_ptr[N]=run;
  }
}

__global__ void k_scan3(const int* __restrict__ counts, const int* __restrict__ partials,
                        int* __restrict__ row_ptr, int* __restrict__ cursor, int N){
  __shared__ int sd[256];
  int t=threadIdx.x;
  int base = blockIdx.x*1024 + t*4;
  int v[4]; int s=0;
  #pragma unroll
  for (int j=0;j<4;j++){ int i=base+j; v[j]=(i<N)?counts[i]:0; s+=v[j]; }
  sd[t]=s; __syncthreads();
  for (int off=1; off<256; off<<=1){
    int x = (t>=off)? sd[t-off] : 0;
    __syncthreads();
    sd[t] += x;
    __syncthreads();
  }
  int run = sd[t]-s + partials[blockIdx.x];   // exclusive offset for this thread
  #pragma unroll
  for (int j=0;j<4;j++){ int i=base+j; if (i<N){ row_ptr[i]=run; cursor[i]=run; } run+=v[j]; }
}

__global__ void k_scatter(const int* __restrict__ src, const int* __restrict__ dst,
                          int* __restrict__ cursor, int* __restrict__ elist,
                          int* __restrict__ slist, int E){
  int e = blockIdx.x*256+threadIdx.x;
  if (e<E){
    int d = dst[e];
    int p = atomicAdd(&cursor[d],1);
    elist[p]=e; slist[p]=src[e];
  }
}

// ---------- W_comb = W_an * W_msg ; Mfull = [W_ah | W_comb] ; Wb = W_an * b_m ----------
__global__ void k_comb(const float* __restrict__ Wa, const float* __restrict__ Wm,
                       const float* __restrict__ bm, float* __restrict__ Mfull,
                       float* __restrict__ Wb){
  int o = blockIdx.x; int t = threadIdx.x;
  if (t < 128){
    Mfull[o*384+t] = Wa[o*256+t];
  } else {
    int i = t-128;
    float s=0.f;
    #pragma unroll 4
    for (int p=0;p<128;p++) s += Wa[o*256+128+p]*Wm[p*256+i];
    Mfull[o*384+t] = s;
  }
  if (t==0){
    float s=0.f;
    for (int p=0;p<128;p++) s += Wa[o*256+128+p]*bm[p];
    Wb[o]=s;
  }
}

// ---------- per-node aggregation: S[n] = [sum h_src ; sum e] * 1/max(deg,1) ----------
__global__ void k_agg(const float* __restrict__ nf, const float* __restrict__ ef,
                      const int* __restrict__ rp, const int* __restrict__ elist,
                      const int* __restrict__ slist, float* __restrict__ S, int N){
  int n = blockIdx.x*4 + (threadIdx.x>>6);
  int lane = threadIdx.x & 63;
  if (n>=N) return;
  int r0 = rp[n], r1 = rp[n+1];
  float dinv = 1.0f/fmaxf((float)(r1-r0),1.0f);
  float aH0=0.f,aH1=0.f,aE0=0.f,aE1=0.f;
  for (int j=r0;j<r1;j++){
    int e=elist[j], s=slist[j];
    float2 h2 = reinterpret_cast<const float2*>(nf + (size_t)s*D)[lane];
    float2 e2 = reinterpret_cast<const float2*>(ef + (size_t)e*D)[lane];
    aH0+=h2.x; aH1+=h2.y; aE0+=e2.x; aE1+=e2.y;
  }
  float2* So = reinterpret_cast<float2*>(S + (size_t)n*256);
  So[lane]    = make_float2(aH0*dinv, aH1*dinv);
  So[64+lane] = make_float2(aE0*dinv, aE1*dinv);
}

// ---------- new_h = relu([nf|S] * Mfull^T + b_a + flag*Wb) ----------
// block: 256 thr (16x16), tile 128 nodes x 128 outs, 8x8 acc/thread, K=384 in chunks of 32.
// LDS tiles stored TRANSPOSED [k][row] (stride 132 = 16B-aligned pad) so the inner
// loop needs only 4 ds_read_b128 (16 live temps) per k-step -> no VGPR spill.
#define LDST 132
__global__ __launch_bounds__(256, 2) void k_gemm(
    const float* __restrict__ nf, const float* __restrict__ S,
    const float* __restrict__ Mfull, const float* __restrict__ ba,
    const float* __restrict__ Wb, const int* __restrict__ rp,
    float* __restrict__ outH, int N)
{
  __shared__ float Xs[32*LDST];
  __shared__ float Ms[32*LDST];
  int tid = threadIdx.x;
  int tx = tid & 15, ty = tid >> 4;
  int bn = blockIdx.x * 128;

  float acc[8][8];
  #pragma unroll
  for (int i=0;i<8;i++)
    #pragma unroll
    for (int j=0;j<8;j++) acc[i][j]=0.f;

  int sr = tid >> 3;          // 0..31 (row within pass)
  int sc = (tid & 7) << 2;    // k offset within tile: 0,4,...,28

  for (int kb = 0; kb < 384; kb += 32){
    __syncthreads();
    #pragma unroll
    for (int pass=0; pass<4; pass++){
      int row = sr + pass*32;
      int n = bn + row; int nn = (n<N)? n : 0;
      const float* xsrc = (kb < 128) ? (nf + (size_t)nn*128 + kb + sc)
                                     : (S  + (size_t)nn*256 + (kb-128) + sc);
      float4 xv = *reinterpret_cast<const float4*>(xsrc);
      float4 mv = *reinterpret_cast<const float4*>(Mfull + (size_t)row*384 + kb + sc);
      Xs[(sc+0)*LDST + row] = xv.x;
      Xs[(sc+1)*LDST + row] = xv.y;
      Xs[(sc+2)*LDST + row] = xv.z;
      Xs[(sc+3)*LDST + row] = xv.w;
      Ms[(sc+0)*LDST + row] = mv.x;
      Ms[(sc+1)*LDST + row] = mv.y;
      Ms[(sc+2)*LDST + row] = mv.z;
      Ms[(sc+3)*LDST + row] = mv.w;
    }
    __syncthreads();
    #pragma unroll
    for (int kk=0; kk<32; kk++){
      float4 xlo = *reinterpret_cast<const float4*>(&Xs[kk*LDST + 4*tx]);
      float4 xhi = *reinterpret_cast<const float4*>(&Xs[kk*LDST + 64 + 4*tx]);
      float4 mlo = *reinterpret_cast<const float4*>(&Ms[kk*LDST + 4*ty]);
      float4 mhi = *reinterpret_cast<const float4*>(&Ms[kk*LDST + 64 + 4*ty]);
      float x0=xlo.x,x1=xlo.y,x2=xlo.z,x3=xlo.w,x4=xhi.x,x5=xhi.y,x6=xhi.z,x7=xhi.w;
      float m0=mlo.x,m1=mlo.y,m2=mlo.z,m3=mlo.w,m4=mhi.x,m5=mhi.y,m6=mhi.z,m7=mhi.w;
      acc[0][0]+=x0*m0; acc[0][1]+=x0*m1; acc[0][2]+=x0*m2; acc[0][3]+=x0*m3;
      acc[0][4]+=x0*m4; acc[0][5]+=x0*m5; acc[0][6]+=x0*m6; acc[0][7]+=x0*m7;
      acc[1][0]+=x1*m0; acc[1][1]+=x1*m1; acc[1][2]+=x1*m2; acc[1][3]+=x1*m3;
      acc[1][4]+=x1*m4; acc[1][5]+=x1*m5; acc[1][6]+=x1*m6; acc[1][7]+=x1*m7;
      acc[2][0]+=x2*m0; acc[2][1]+=x2*m1; acc[2][2]+=x2*m2; acc[2][3]+=x2*m3;
      acc[2][4]+=x2*m4; acc[2][5]+=x2*m5; acc[2][6]+=x2*m6; acc[2][7]+=x2*m7;
      acc[3][0]+=x3*m0; acc[3][1]+=x3*m1; acc[3][2]+=x3*m2; acc[3][3]+=x3*m3;
      acc[3][4]+=x3*m4; acc[3][5]+=x3*m5; acc[3][6]+=x3*m6; acc[3][7]+=x3*m7;
      acc[4][0]+=x4*m0; acc[4][1]+=x4*m1; acc[4][2]+=x4*m2; acc[4][3]+=x4*m3;
      acc[4][4]+=x4*m4; acc[4][5]+=x4*m5; acc[4][6]+=x4*m6; acc[4][7]+=x4*m7;
      acc[5][0]+=x5*m0; acc[5][1]+=x5*m1; acc[5][2]+=x5*m2; acc[5][3]+=x5*m3;
      acc[5][4]+=x5*m4; acc[5][5]+=x5*m5; acc[5][6]+=x5*m6; acc[5][7]+=x5*m7;
      acc[6][0]+=x6*m0; acc[6][1]+=x6*m1; acc[6][2]+=x6*m2; acc[6][3]+=x6*m3;
      acc[6][4]+=x6*m4; acc[6][5]+=x6*m5; acc[6][6]+=x6*m6; acc[6][7]+=x6*m7;
      acc[7][0]+=x7*m0; acc[7][1]+=x7*m1; acc[7][2]+=x7*m2; acc[7][3]+=x7*m3;
      acc[7][4]+=x7*m4; acc[7][5]+=x7*m5; acc[7][6]+=x7*m6; acc[7][7]+=x7*m7;
    }
  }

  float4 ba_a = *reinterpret_cast<const float4*>(ba + 4*ty);
  float4 ba_b = *reinterpret_cast<const float4*>(ba + 64 + 4*ty);
  float4 wb_a = *reinterpret_cast<const float4*>(Wb + 4*ty);
  float4 wb_b = *reinterpret_cast<const float4*>(Wb + 64 + 4*ty);
  #pragma unroll
  for (int i=0;i<8;i++){
    int n = (i<4) ? (bn + 4*tx + i) : (bn + 64 + 4*tx + (i-4));
    if (n < N){
      float flag = (rp[n+1]-rp[n] > 0) ? 1.0f : 0.0f;
      float4 o1, o2;
      o1.x = fmaxf(acc[i][0] + ba_a.x + flag*wb_a.x, 0.f);
      o1.y = fmaxf(acc[i][1] + ba_a.y + flag*wb_a.y, 0.f);
      o1.z = fmaxf(acc[i][2] + ba_a.z + flag*wb_a.z, 0.f);
      o1.w = fmaxf(acc[i][3] + ba_a.w + flag*wb_a.w, 0.f);
      o2.x = fmaxf(acc[i][4] + ba_b.x + flag*wb_b.x, 0.f);
      o2.y = fmaxf(acc[i][5] + ba_b.y + flag*wb_b.y, 0.f);
      o2.z = fmaxf(acc[i][6] + ba_b.z + flag*wb_b.z, 0.f);
      o2.w = fmaxf(acc[i][7] + ba_b.w + flag*wb_b.w, 0.f);
      *reinterpret_cast<float4*>(outH + (size_t)n*128 + 4*ty)      = o1;
      *reinterpret_cast<float4*>(outH + (size_t)n*128 + 64 + 4*ty) = o2;
    }
  }
}

// ---------- new_e = 0.5*(new_h[src] + new_h[dst]) ----------
__global__ void k_edge(const int* __restrict__ src, const int* __restrict__ dst,
                       const float* __restrict__ H, float* __restrict__ NE, int E){
  int t = threadIdx.x;
  int e = blockIdx.x*8 + (t>>5);
  if (e>=E) return;
  int l = t & 31;
  const float4* Hs = reinterpret_cast<const float4*>(H + (size_t)src[e]*D);
  const float4* Hd = reinterpret_cast<const float4*>(H + (size_t)dst[e]*D);
  float4 a = Hs[l], b = Hd[l];
  float4 r;
  r.x = 0.5f*(a.x+b.x); r.y = 0.5f*(a.y+b.y);
  r.z = 0.5f*(a.z+b.z); r.w = 0.5f*(a.w+b.w);
  reinterpret_cast<float4*>(NE + (size_t)e*D)[l] = r;
}

extern "C" void kernel_launch(void* const* d_in, const int* in_sizes, int n_in,
                              void* d_out, int out_size, void* d_ws, size_t ws_size,
                              hipStream_t stream)
{
  const float* nf  = (const float*)d_in[0];
  const float* ef  = (const float*)d_in[1];
  const int*   src = (const int*)d_in[2];
  const int*   dst = (const int*)d_in[3];
  const float* Wm  = (const float*)d_in[4];
  const float* bm  = (const float*)d_in[5];
  const float* Wa  = (const float*)d_in[6];
  const float* bap = (const float*)d_in[7];
  int N = in_sizes[0]/D;
  int E = in_sizes[2];
  float* outH = (float*)d_out;
  float* outE = (float*)d_out + (size_t)N*D;

  // carve workspace (falls back to the new_e region of d_out, overwritten last)
  size_t off = 0;
  auto alloc = [&](size_t bytes){ size_t o = off; off = (off + bytes + 255) & ~(size_t)255; return o; };
  size_t o_counts = alloc((size_t)N*4);
  size_t o_rp     = alloc((size_t)(N+1)*4);
  size_t o_part   = alloc(1024*4);
  size_t o_cur    = alloc((size_t)N*4);
  size_t o_el     = alloc((size_t)E*4);
  size_t o_sl     = alloc((size_t)E*4);
  size_t o_M      = alloc((size_t)128*384*4);
  size_t o_wb     = alloc(128*4);
  size_t o_S      = alloc((size_t)N*256*4);
  size_t need = off;
  char* base = (ws_size >= need) ? (char*)d_ws : (char*)(void*)outE;

  int* counts  = (int*)(base + o_counts);
  int* row_ptr = (int*)(base + o_rp);
  int* partials= (int*)(base + o_part);
  int* cursor  = (int*)(base + o_cur);
  int* elist   = (int*)(base + o_el);
  int* slist   = (int*)(base + o_sl);
  float* Mfull = (float*)(base + o_M);
  float* Wb    = (float*)(base + o_wb);
  float* S     = (float*)(base + o_S);

  hipMemsetAsync(counts, 0, (size_t)N*4, stream);

  int NB = (N + 1023)/1024;
  k_hist   <<<(E+255)/256, 256, 0, stream>>>(dst, counts, E);
  k_scan1  <<<NB, 256, 0, stream>>>(counts, partials, N);
  k_scan2  <<<1, 64, 0, stream>>>(partials, row_ptr, NB, N);
  k_scan3  <<<NB, 256, 0, stream>>>(counts, partials, row_ptr, cursor, N);
  k_scatter<<<(E+255)/256, 256, 0, stream>>>(src, dst, cursor, elist, slist, E);
  k_comb   <<<128, 384, 0, stream>>>(Wa, Wm, bm, Mfull, Wb);
  k_agg    <<<(N+3)/4, 256, 0, stream>>>(nf, ef, row_ptr, elist, slist, S, N);
  k_gemm   <<<(N+127)/128, 256, 0, stream>>>(nf, S, Mfull, bap, Wb, row_ptr, outH, N);
  k_edge   <<<(E+7)/8, 256, 0, stream>>>(src, dst, outH, outE, E);
}

// Round 3
// 500.691 us; speedup vs baseline: 6.3169x; 1.2461x over previous
//
#include <hip/hip_runtime.h>

#define D 128

typedef __attribute__((ext_vector_type(4))) float f32x4;
typedef __attribute__((ext_vector_type(8))) short s16x8;

__device__ inline unsigned short f2bf(float x){
  unsigned u = __builtin_bit_cast(unsigned, x);
  u += 0x7FFFu + ((u>>16)&1u);
  return (unsigned short)(u>>16);
}

__device__ inline void gload_lds16(const void* g, void* l){
  __builtin_amdgcn_global_load_lds(
      (const __attribute__((address_space(1))) void*)g,
      (__attribute__((address_space(3))) void*)l, 16, 0, 0);
}

// ---------- CSR build ----------
__global__ void k_hist(const int* __restrict__ dst, int* __restrict__ counts, int E){
  int e = blockIdx.x*256 + threadIdx.x;
  if (e < E) atomicAdd(&counts[dst[e]], 1);
}

__global__ void k_scan1(const int* __restrict__ counts, int* __restrict__ partials, int N){
  __shared__ int sd[256];
  int t = threadIdx.x;
  int base = blockIdx.x*1024 + t*4;
  int s = 0;
  #pragma unroll
  for (int j=0;j<4;j++){ int i=base+j; s += (i<N)?counts[i]:0; }
  sd[t]=s; __syncthreads();
  for (int off=128; off>0; off>>=1){ if (t<off) sd[t]+=sd[t+off]; __syncthreads(); }
  if (t==0) partials[blockIdx.x]=sd[0];
}

__global__ void k_scan2(int* __restrict__ partials, int* __restrict__ row_ptr, int nb, int N){
  if (blockIdx.x==0 && threadIdx.x==0){
    int run=0;
    for (int b=0;b<nb;b++){ int v=partials[b]; partials[b]=run; run+=v; }
    row_ptr[N]=run;
  }
}

__global__ void k_scan3(const int* __restrict__ counts, const int* __restrict__ partials,
                        int* __restrict__ row_ptr, int* __restrict__ cursor, int N){
  __shared__ int sd[256];
  int t=threadIdx.x;
  int base = blockIdx.x*1024 + t*4;
  int v[4]; int s=0;
  #pragma unroll
  for (int j=0;j<4;j++){ int i=base+j; v[j]=(i<N)?counts[i]:0; s+=v[j]; }
  sd[t]=s; __syncthreads();
  for (int off=1; off<256; off<<=1){
    int x = (t>=off)? sd[t-off] : 0;
    __syncthreads();
    sd[t] += x;
    __syncthreads();
  }
  int run = sd[t]-s + partials[blockIdx.x];
  #pragma unroll
  for (int j=0;j<4;j++){ int i=base+j; if (i<N){ row_ptr[i]=run; cursor[i]=run; } run+=v[j]; }
}

__global__ void k_scatter(const int* __restrict__ src, const int* __restrict__ dst,
                          int* __restrict__ cursor, int2* __restrict__ es, int E){
  int e = blockIdx.x*256+threadIdx.x;
  if (e<E){
    int d = dst[e];
    int p = atomicAdd(&cursor[d],1);
    int2 v; v.x = e; v.y = src[e];
    es[p] = v;
  }
}

// ---------- nf -> bf16 ----------
__global__ void k_cvt(const float* __restrict__ in, unsigned short* __restrict__ out, int n8){
  int i = blockIdx.x*256 + threadIdx.x;
  if (i >= n8) return;
  const float4* p = reinterpret_cast<const float4*>(in) + (size_t)i*2;
  float4 a = p[0], b = p[1];
  union { unsigned short s[8]; uint4 u; } r;
  r.s[0]=f2bf(a.x); r.s[1]=f2bf(a.y); r.s[2]=f2bf(a.z); r.s[3]=f2bf(a.w);
  r.s[4]=f2bf(b.x); r.s[5]=f2bf(b.y); r.s[6]=f2bf(b.z); r.s[7]=f2bf(b.w);
  reinterpret_cast<uint4*>(out)[i] = r.u;
}

// ---------- Mbf = bf16([W_ah | W_an*W_msg]) ; Wb = W_an * b_m ----------
__global__ void k_comb(const float* __restrict__ Wa, const float* __restrict__ Wm,
                       const float* __restrict__ bm, unsigned short* __restrict__ Mbf,
                       float* __restrict__ Wb){
  int o = blockIdx.x; int t = threadIdx.x;
  if (t < 128){
    Mbf[o*384+t] = f2bf(Wa[o*256+t]);
  } else {
    int i = t-128;
    float s=0.f;
    #pragma unroll 4
    for (int p=0;p<128;p++) s += Wa[o*256+128+p]*Wm[p*256+i];
    Mbf[o*384+t] = f2bf(s);
  }
  if (t==0){
    float s=0.f;
    for (int p=0;p<128;p++) s += Wa[o*256+128+p]*bm[p];
    Wb[o]=s;
  }
}

// ---------- per-node aggregation -> bf16 S + deg flag ----------
__global__ void k_agg(const float* __restrict__ nf, const float* __restrict__ ef,
                      const int* __restrict__ rp, const int2* __restrict__ es,
                      unsigned short* __restrict__ Sbf, float* __restrict__ flagA, int N){
  int n = blockIdx.x*4 + (threadIdx.x>>6);
  int lane = threadIdx.x & 63;
  if (n>=N) return;
  int r0 = rp[n], r1 = rp[n+1];
  float dinv = 1.0f/fmaxf((float)(r1-r0),1.0f);
  float aH0=0.f,aH1=0.f,aE0=0.f,aE1=0.f;
  for (int j=r0;j<r1;j++){
    int2 p = es[j];
    float2 h2 = reinterpret_cast<const float2*>(nf + (size_t)p.y*D)[lane];
    float2 e2 = reinterpret_cast<const float2*>(ef + (size_t)p.x*D)[lane];
    aH0+=h2.x; aH1+=h2.y; aE0+=e2.x; aE1+=e2.y;
  }
  ushort2* So = reinterpret_cast<ushort2*>(Sbf + (size_t)n*256);
  ushort2 th; th.x = f2bf(aH0*dinv); th.y = f2bf(aH1*dinv);
  ushort2 te; te.x = f2bf(aE0*dinv); te.y = f2bf(aE1*dinv);
  So[lane]    = th;
  So[64+lane] = te;
  if (lane==0) flagA[n] = (r1>r0) ? 1.0f : 0.0f;
}

// ---------- new_h = relu([nf|S]_bf16 * Mbf^T + ba + flag*Wb), MFMA ----------
// 128x128 tile, 4 waves (2x2 of 64x64), K=384 in 12 chunks of 32.
// LDS: A[128][32] bf16, B[128 outs][32] bf16, staged via global_load_lds w=16.
__global__ __launch_bounds__(256) void k_gemm(
    const unsigned short* __restrict__ nfb, const unsigned short* __restrict__ Sbf,
    const unsigned short* __restrict__ Mbf, const float* __restrict__ ba,
    const float* __restrict__ Wb, const float* __restrict__ flagA,
    float* __restrict__ outH, int N)
{
  __shared__ __align__(16) unsigned short As[128*32];
  __shared__ __align__(16) unsigned short Bs[128*32];
  int tid = threadIdx.x;
  int lane = tid & 63;
  int w = tid >> 6;
  int wr = w >> 1, wc = w & 1;
  int bn = blockIdx.x * 128;

  f32x4 acc[4][4];
  #pragma unroll
  for (int i=0;i<4;i++)
    #pragma unroll
    for (int j=0;j<4;j++) acc[i][j] = (f32x4){0.f,0.f,0.f,0.f};

  int lr = lane >> 2;            // 0..15: row within a 16-row staging call
  int lb = (lane & 3) * 16;      // byte offset within the 64B row chunk

  for (int kb = 0; kb < 384; kb += 32){
    #pragma unroll
    for (int c = 0; c < 2; c++){
      int rbase = w*32 + c*16;
      int row = rbase + lr;
      int n = bn + row; if (n >= N) n = N-1;
      const char* g;
      if (kb < 128) g = (const char*)nfb + (size_t)n*256 + (size_t)kb*2 + lb;
      else          g = (const char*)Sbf + (size_t)n*512 + (size_t)(kb-128)*2 + lb;
      gload_lds16(g, &As[rbase*32]);
      const char* gm = (const char*)Mbf + (size_t)row*768 + (size_t)kb*2 + lb;
      gload_lds16(gm, &Bs[rbase*32]);
    }
    __syncthreads();
    s16x8 af[4], bfr[4];
    int kg = (lane>>4)*8;
    #pragma unroll
    for (int bi=0;bi<4;bi++)
      af[bi] = *reinterpret_cast<const s16x8*>(&As[(wr*64 + bi*16 + (lane&15))*32 + kg]);
    #pragma unroll
    for (int bj=0;bj<4;bj++)
      bfr[bj] = *reinterpret_cast<const s16x8*>(&Bs[(wc*64 + bj*16 + (lane&15))*32 + kg]);
    #pragma unroll
    for (int bi=0;bi<4;bi++)
      #pragma unroll
      for (int bj=0;bj<4;bj++)
        acc[bi][bj] = __builtin_amdgcn_mfma_f32_16x16x32_bf16(af[bi], bfr[bj], acc[bi][bj], 0, 0, 0);
    __syncthreads();
  }

  float bav[4], wbv[4];
  #pragma unroll
  for (int bj=0;bj<4;bj++){
    int col = wc*64 + bj*16 + (lane&15);
    bav[bj] = ba[col]; wbv[bj] = Wb[col];
  }
  #pragma unroll
  for (int bi=0;bi<4;bi++){
    int rb = bn + wr*64 + bi*16 + (lane>>4)*4;
    #pragma unroll
    for (int r=0;r<4;r++){
      int row = rb + r;
      if (row < N){
        float fl = flagA[row];
        #pragma unroll
        for (int bj=0;bj<4;bj++){
          int col = wc*64 + bj*16 + (lane&15);
          float v = acc[bi][bj][r] + bav[bj] + fl*wbv[bj];
          outH[(size_t)row*128 + col] = fmaxf(v, 0.f);
        }
      }
    }
  }
}

// ---------- new_e in CSR order: H[dst] kept in regs, gather H[src] ----------
__global__ void k_edge_csr(const float* __restrict__ H, const int* __restrict__ rp,
                           const int2* __restrict__ es, float* __restrict__ NE, int N){
  int n = blockIdx.x*4 + (threadIdx.x>>6);
  int lane = threadIdx.x & 63;
  if (n>=N) return;
  int r0 = rp[n], r1 = rp[n+1];
  float2 hn = reinterpret_cast<const float2*>(H + (size_t)n*D)[lane];
  for (int j=r0;j<r1;j++){
    int2 p = es[j];
    float2 hs = reinterpret_cast<const float2*>(H + (size_t)p.y*D)[lane];
    float2 o; o.x = 0.5f*(hn.x+hs.x); o.y = 0.5f*(hn.y+hs.y);
    reinterpret_cast<float2*>(NE + (size_t)p.x*D)[lane] = o;
  }
}

// fallback (workspace-in-output mode): sequential-e version reading only inputs
__global__ void k_edge(const int* __restrict__ src, const int* __restrict__ dst,
                       const float* __restrict__ H, float* __restrict__ NE, int E){
  int t = threadIdx.x;
  int e = blockIdx.x*8 + (t>>5);
  if (e>=E) return;
  int l = t & 31;
  const float4* Hs = reinterpret_cast<const float4*>(H + (size_t)src[e]*D);
  const float4* Hd = reinterpret_cast<const float4*>(H + (size_t)dst[e]*D);
  float4 a = Hs[l], b = Hd[l];
  float4 r;
  r.x = 0.5f*(a.x+b.x); r.y = 0.5f*(a.y+b.y);
  r.z = 0.5f*(a.z+b.z); r.w = 0.5f*(a.w+b.w);
  reinterpret_cast<float4*>(NE + (size_t)e*D)[l] = r;
}

extern "C" void kernel_launch(void* const* d_in, const int* in_sizes, int n_in,
                              void* d_out, int out_size, void* d_ws, size_t ws_size,
                              hipStream_t stream)
{
  const float* nf  = (const float*)d_in[0];
  const float* ef  = (const float*)d_in[1];
  const int*   src = (const int*)d_in[2];
  const int*   dst = (const int*)d_in[3];
  const float* Wm  = (const float*)d_in[4];
  const float* bm  = (const float*)d_in[5];
  const float* Wa  = (const float*)d_in[6];
  const float* bap = (const float*)d_in[7];
  int N = in_sizes[0]/D;
  int E = in_sizes[2];
  float* outH = (float*)d_out;
  float* outE = (float*)d_out + (size_t)N*D;

  size_t off = 0;
  auto alloc = [&](size_t bytes){ size_t o = off; off = (off + bytes + 255) & ~(size_t)255; return o; };
  size_t o_counts = alloc((size_t)N*4);
  size_t o_rp     = alloc((size_t)(N+1)*4);
  size_t o_part   = alloc(1024*4);
  size_t o_cur    = alloc((size_t)N*4);
  size_t o_es     = alloc((size_t)E*8);
  size_t o_M      = alloc((size_t)128*384*2);
  size_t o_wb     = alloc(128*4);
  size_t o_S      = alloc((size_t)N*256*2);
  size_t o_nfb    = alloc((size_t)N*128*2);
  size_t o_flag   = alloc((size_t)N*4);
  size_t need = off;
  bool ws_ok = (ws_size >= need);
  char* base = ws_ok ? (char*)d_ws : (char*)(void*)outE;

  int* counts  = (int*)(base + o_counts);
  int* row_ptr = (int*)(base + o_rp);
  int* partials= (int*)(base + o_part);
  int* cursor  = (int*)(base + o_cur);
  int2* es     = (int2*)(base + o_es);
  unsigned short* Mbf = (unsigned short*)(base + o_M);
  float* Wb    = (float*)(base + o_wb);
  unsigned short* Sbf = (unsigned short*)(base + o_S);
  unsigned short* nfb = (unsigned short*)(base + o_nfb);
  float* flagA = (float*)(base + o_flag);

  hipMemsetAsync(counts, 0, (size_t)N*4, stream);

  int NB = (N + 1023)/1024;
  k_hist   <<<(E+255)/256, 256, 0, stream>>>(dst, counts, E);
  k_scan1  <<<NB, 256, 0, stream>>>(counts, partials, N);
  k_scan2  <<<1, 64, 0, stream>>>(partials, row_ptr, NB, N);
  k_scan3  <<<NB, 256, 0, stream>>>(counts, partials, row_ptr, cursor, N);
  k_scatter<<<(E+255)/256, 256, 0, stream>>>(src, dst, cursor, es, E);
  k_comb   <<<128, 384, 0, stream>>>(Wa, Wm, bm, Mbf, Wb);
  k_cvt    <<<(N*16 + 255)/256, 256, 0, stream>>>(nf, nfb, N*16);
  k_agg    <<<(N+3)/4, 256, 0, stream>>>(nf, ef, row_ptr, es, Sbf, flagA, N);
  k_gemm   <<<(N+127)/128, 256, 0, stream>>>(nfb, Sbf, Mbf, bap, Wb, flagA, outH, N);
  if (ws_ok)
    k_edge_csr<<<(N+3)/4, 256, 0, stream>>>(outH, row_ptr, es, outE, N);
  else
    k_edge    <<<(E+7)/8, 256, 0, stream>>>(src, dst, outH, outE, E);
}

// Round 4
// 439.088 us; speedup vs baseline: 7.2032x; 1.1403x over previous
//
#include <hip/hip_runtime.h>

#define D 128

typedef __attribute__((ext_vector_type(4))) float f32x4;
typedef __attribute__((ext_vector_type(8))) short s16x8;

__device__ inline unsigned short f2bf(float x){
  unsigned u = __builtin_bit_cast(unsigned, x);
  u += 0x7FFFu + ((u>>16)&1u);
  return (unsigned short)(u>>16);
}

__device__ inline void gload_lds16(const void* g, void* l){
  __builtin_amdgcn_global_load_lds(
      (const __attribute__((address_space(1))) void*)g,
      (__attribute__((address_space(3))) void*)l, 16, 0, 0);
}

// ---------- CSR build ----------
__global__ void k_hist(const int* __restrict__ dst, int* __restrict__ counts, int E){
  int e = blockIdx.x*256 + threadIdx.x;
  if (e < E) atomicAdd(&counts[dst[e]], 1);
}

__global__ void k_scan1(const int* __restrict__ counts, int* __restrict__ partials, int N){
  __shared__ int sd[256];
  int t = threadIdx.x;
  int base = blockIdx.x*1024 + t*4;
  int s = 0;
  #pragma unroll
  for (int j=0;j<4;j++){ int i=base+j; s += (i<N)?counts[i]:0; }
  sd[t]=s; __syncthreads();
  for (int off=128; off>0; off>>=1){ if (t<off) sd[t]+=sd[t+off]; __syncthreads(); }
  if (t==0) partials[blockIdx.x]=sd[0];
}

// parallel exclusive scan over up to 1024 partials in one block
__global__ void k_scan2(int* __restrict__ partials, int* __restrict__ row_ptr, int nb, int N){
  __shared__ int sd[1024];
  int t = threadIdx.x;
  if (nb <= 1024){
    int v = (t < nb) ? partials[t] : 0;
    sd[t] = v;
    __syncthreads();
    #pragma unroll
    for (int off=1; off<1024; off<<=1){
      int x = (t >= off) ? sd[t-off] : 0;
      __syncthreads();
      sd[t] += x;
      __syncthreads();
    }
    if (t < nb) partials[t] = sd[t] - v;   // exclusive
    if (t == 1023) row_ptr[N] = sd[1023];  // total
  } else if (t == 0){
    int run=0;
    for (int b=0;b<nb;b++){ int v=partials[b]; partials[b]=run; run+=v; }
    row_ptr[N]=run;
  }
}

__global__ void k_scan3(const int* __restrict__ counts, const int* __restrict__ partials,
                        int* __restrict__ row_ptr, int* __restrict__ cursor, int N){
  __shared__ int sd[256];
  int t=threadIdx.x;
  int base = blockIdx.x*1024 + t*4;
  int v[4]; int s=0;
  #pragma unroll
  for (int j=0;j<4;j++){ int i=base+j; v[j]=(i<N)?counts[i]:0; s+=v[j]; }
  sd[t]=s; __syncthreads();
  for (int off=1; off<256; off<<=1){
    int x = (t>=off)? sd[t-off] : 0;
    __syncthreads();
    sd[t] += x;
    __syncthreads();
  }
  int run = sd[t]-s + partials[blockIdx.x];
  #pragma unroll
  for (int j=0;j<4;j++){ int i=base+j; if (i<N){ row_ptr[i]=run; cursor[i]=run; } run+=v[j]; }
}

__global__ void k_scatter(const int* __restrict__ src, const int* __restrict__ dst,
                          int* __restrict__ cursor, int2* __restrict__ es, int E){
  int e = blockIdx.x*256+threadIdx.x;
  if (e<E){
    int d = dst[e];
    int p = atomicAdd(&cursor[d],1);
    int2 v; v.x = e; v.y = src[e];
    es[p] = v;
  }
}

// ---------- nf -> bf16 ----------
__global__ void k_cvt(const float* __restrict__ in, unsigned short* __restrict__ out, int n8){
  int i = blockIdx.x*256 + threadIdx.x;
  if (i >= n8) return;
  const float4* p = reinterpret_cast<const float4*>(in) + (size_t)i*2;
  float4 a = p[0], b = p[1];
  union { unsigned short s[8]; uint4 u; } r;
  r.s[0]=f2bf(a.x); r.s[1]=f2bf(a.y); r.s[2]=f2bf(a.z); r.s[3]=f2bf(a.w);
  r.s[4]=f2bf(b.x); r.s[5]=f2bf(b.y); r.s[6]=f2bf(b.z); r.s[7]=f2bf(b.w);
  reinterpret_cast<uint4*>(out)[i] = r.u;
}

// ---------- Mbf = bf16([W_ah | W_an*W_msg]) ; Wb = W_an * b_m ----------
__global__ void k_comb(const float* __restrict__ Wa, const float* __restrict__ Wm,
                       const float* __restrict__ bm, unsigned short* __restrict__ Mbf,
                       float* __restrict__ Wb){
  int o = blockIdx.x; int t = threadIdx.x;
  if (t < 128){
    Mbf[o*384+t] = f2bf(Wa[o*256+t]);
  } else {
    int i = t-128;
    float s=0.f;
    #pragma unroll 4
    for (int p=0;p<128;p++) s += Wa[o*256+128+p]*Wm[p*256+i];
    Mbf[o*384+t] = f2bf(s);
  }
  if (t==0){
    float s=0.f;
    for (int p=0;p<128;p++) s += Wa[o*256+128+p]*bm[p];
    Wb[o]=s;
  }
}

// ---------- per-node aggregation -> bf16 S + deg flag (unroll-4 gather) ----------
__global__ void k_agg(const float* __restrict__ nf, const float* __restrict__ ef,
                      const int* __restrict__ rp, const int2* __restrict__ es,
                      unsigned short* __restrict__ Sbf, float* __restrict__ flagA, int N){
  int n = blockIdx.x*4 + (threadIdx.x>>6);
  int lane = threadIdx.x & 63;
  if (n>=N) return;
  int r0 = rp[n], r1 = rp[n+1];
  float dinv = 1.0f/fmaxf((float)(r1-r0),1.0f);
  float aH0=0.f,aH1=0.f,aE0=0.f,aE1=0.f;
  int j = r0;
  for (; j+4<=r1; j+=4){
    int2 p0=es[j], p1=es[j+1], p2=es[j+2], p3=es[j+3];
    float2 h0 = reinterpret_cast<const float2*>(nf + (size_t)p0.y*D)[lane];
    float2 h1 = reinterpret_cast<const float2*>(nf + (size_t)p1.y*D)[lane];
    float2 h2 = reinterpret_cast<const float2*>(nf + (size_t)p2.y*D)[lane];
    float2 h3 = reinterpret_cast<const float2*>(nf + (size_t)p3.y*D)[lane];
    float2 e0 = reinterpret_cast<const float2*>(ef + (size_t)p0.x*D)[lane];
    float2 e1 = reinterpret_cast<const float2*>(ef + (size_t)p1.x*D)[lane];
    float2 e2 = reinterpret_cast<const float2*>(ef + (size_t)p2.x*D)[lane];
    float2 e3 = reinterpret_cast<const float2*>(ef + (size_t)p3.x*D)[lane];
    aH0 += (h0.x+h1.x)+(h2.x+h3.x);
    aH1 += (h0.y+h1.y)+(h2.y+h3.y);
    aE0 += (e0.x+e1.x)+(e2.x+e3.x);
    aE1 += (e0.y+e1.y)+(e2.y+e3.y);
  }
  for (; j<r1; j++){
    int2 p = es[j];
    float2 h2 = reinterpret_cast<const float2*>(nf + (size_t)p.y*D)[lane];
    float2 e2 = reinterpret_cast<const float2*>(ef + (size_t)p.x*D)[lane];
    aH0+=h2.x; aH1+=h2.y; aE0+=e2.x; aE1+=e2.y;
  }
  ushort2* So = reinterpret_cast<ushort2*>(Sbf + (size_t)n*256);
  ushort2 th; th.x = f2bf(aH0*dinv); th.y = f2bf(aH1*dinv);
  ushort2 te; te.x = f2bf(aE0*dinv); te.y = f2bf(aE1*dinv);
  So[lane]    = th;
  So[64+lane] = te;
  if (lane==0) flagA[n] = (r1>r0) ? 1.0f : 0.0f;
}

// ---------- new_h = relu([nf|S]_bf16 * Mbf^T + ba + flag*Wb), MFMA ----------
__global__ __launch_bounds__(256) void k_gemm(
    const unsigned short* __restrict__ nfb, const unsigned short* __restrict__ Sbf,
    const unsigned short* __restrict__ Mbf, const float* __restrict__ ba,
    const float* __restrict__ Wb, const float* __restrict__ flagA,
    float* __restrict__ outH, int N)
{
  __shared__ __align__(16) unsigned short As[128*32];
  __shared__ __align__(16) unsigned short Bs[128*32];
  int tid = threadIdx.x;
  int lane = tid & 63;
  int w = tid >> 6;
  int wr = w >> 1, wc = w & 1;
  int bn = blockIdx.x * 128;

  f32x4 acc[4][4];
  #pragma unroll
  for (int i=0;i<4;i++)
    #pragma unroll
    for (int j=0;j<4;j++) acc[i][j] = (f32x4){0.f,0.f,0.f,0.f};

  int lr = lane >> 2;
  int lb = (lane & 3) * 16;

  for (int kb = 0; kb < 384; kb += 32){
    #pragma unroll
    for (int c = 0; c < 2; c++){
      int rbase = w*32 + c*16;
      int row = rbase + lr;
      int n = bn + row; if (n >= N) n = N-1;
      const char* g;
      if (kb < 128) g = (const char*)nfb + (size_t)n*256 + (size_t)kb*2 + lb;
      else          g = (const char*)Sbf + (size_t)n*512 + (size_t)(kb-128)*2 + lb;
      gload_lds16(g, &As[rbase*32]);
      const char* gm = (const char*)Mbf + (size_t)row*768 + (size_t)kb*2 + lb;
      gload_lds16(gm, &Bs[rbase*32]);
    }
    __syncthreads();
    s16x8 af[4], bfr[4];
    int kg = (lane>>4)*8;
    #pragma unroll
    for (int bi=0;bi<4;bi++)
      af[bi] = *reinterpret_cast<const s16x8*>(&As[(wr*64 + bi*16 + (lane&15))*32 + kg]);
    #pragma unroll
    for (int bj=0;bj<4;bj++)
      bfr[bj] = *reinterpret_cast<const s16x8*>(&Bs[(wc*64 + bj*16 + (lane&15))*32 + kg]);
    #pragma unroll
    for (int bi=0;bi<4;bi++)
      #pragma unroll
      for (int bj=0;bj<4;bj++)
        acc[bi][bj] = __builtin_amdgcn_mfma_f32_16x16x32_bf16(af[bi], bfr[bj], acc[bi][bj], 0, 0, 0);
    __syncthreads();
  }

  float bav[4], wbv[4];
  #pragma unroll
  for (int bj=0;bj<4;bj++){
    int col = wc*64 + bj*16 + (lane&15);
    bav[bj] = ba[col]; wbv[bj] = Wb[col];
  }
  #pragma unroll
  for (int bi=0;bi<4;bi++){
    int rb = bn + wr*64 + bi*16 + (lane>>4)*4;
    #pragma unroll
    for (int r=0;r<4;r++){
      int row = rb + r;
      if (row < N){
        float fl = flagA[row];
        #pragma unroll
        for (int bj=0;bj<4;bj++){
          int col = wc*64 + bj*16 + (lane&15);
          float v = acc[bi][bj][r] + bav[bj] + fl*wbv[bj];
          outH[(size_t)row*128 + col] = fmaxf(v, 0.f);
        }
      }
    }
  }
}

// ---------- new_e in CSR order (unroll-4): H[dst] in regs, gather H[src] ----------
__global__ void k_edge_csr(const float* __restrict__ H, const int* __restrict__ rp,
                           const int2* __restrict__ es, float* __restrict__ NE, int N){
  int n = blockIdx.x*4 + (threadIdx.x>>6);
  int lane = threadIdx.x & 63;
  if (n>=N) return;
  int r0 = rp[n], r1 = rp[n+1];
  float2 hn = reinterpret_cast<const float2*>(H + (size_t)n*D)[lane];
  int j = r0;
  for (; j+4<=r1; j+=4){
    int2 p0=es[j], p1=es[j+1], p2=es[j+2], p3=es[j+3];
    float2 a0 = reinterpret_cast<const float2*>(H + (size_t)p0.y*D)[lane];
    float2 a1 = reinterpret_cast<const float2*>(H + (size_t)p1.y*D)[lane];
    float2 a2 = reinterpret_cast<const float2*>(H + (size_t)p2.y*D)[lane];
    float2 a3 = reinterpret_cast<const float2*>(H + (size_t)p3.y*D)[lane];
    float2 o;
    o.x=0.5f*(hn.x+a0.x); o.y=0.5f*(hn.y+a0.y);
    reinterpret_cast<float2*>(NE + (size_t)p0.x*D)[lane] = o;
    o.x=0.5f*(hn.x+a1.x); o.y=0.5f*(hn.y+a1.y);
    reinterpret_cast<float2*>(NE + (size_t)p1.x*D)[lane] = o;
    o.x=0.5f*(hn.x+a2.x); o.y=0.5f*(hn.y+a2.y);
    reinterpret_cast<float2*>(NE + (size_t)p2.x*D)[lane] = o;
    o.x=0.5f*(hn.x+a3.x); o.y=0.5f*(hn.y+a3.y);
    reinterpret_cast<float2*>(NE + (size_t)p3.x*D)[lane] = o;
  }
  for (; j<r1; j++){
    int2 p = es[j];
    float2 hs = reinterpret_cast<const float2*>(H + (size_t)p.y*D)[lane];
    float2 o; o.x = 0.5f*(hn.x+hs.x); o.y = 0.5f*(hn.y+hs.y);
    reinterpret_cast<float2*>(NE + (size_t)p.x*D)[lane] = o;
  }
}

// fallback (workspace-in-output mode)
__global__ void k_edge(const int* __restrict__ src, const int* __restrict__ dst,
                       const float* __restrict__ H, float* __restrict__ NE, int E){
  int t = threadIdx.x;
  int e = blockIdx.x*8 + (t>>5);
  if (e>=E) return;
  int l = t & 31;
  const float4* Hs = reinterpret_cast<const float4*>(H + (size_t)src[e]*D);
  const float4* Hd = reinterpret_cast<const float4*>(H + (size_t)dst[e]*D);
  float4 a = Hs[l], b = Hd[l];
  float4 r;
  r.x = 0.5f*(a.x+b.x); r.y = 0.5f*(a.y+b.y);
  r.z = 0.5f*(a.z+b.z); r.w = 0.5f*(a.w+b.w);
  reinterpret_cast<float4*>(NE + (size_t)e*D)[l] = r;
}

extern "C" void kernel_launch(void* const* d_in, const int* in_sizes, int n_in,
                              void* d_out, int out_size, void* d_ws, size_t ws_size,
                              hipStream_t stream)
{
  const float* nf  = (const float*)d_in[0];
  const float* ef  = (const float*)d_in[1];
  const int*   src = (const int*)d_in[2];
  const int*   dst = (const int*)d_in[3];
  const float* Wm  = (const float*)d_in[4];
  const float* bm  = (const float*)d_in[5];
  const float* Wa  = (const float*)d_in[6];
  const float* bap = (const float*)d_in[7];
  int N = in_sizes[0]/D;
  int E = in_sizes[2];
  float* outH = (float*)d_out;
  float* outE = (float*)d_out + (size_t)N*D;

  size_t off = 0;
  auto alloc = [&](size_t bytes){ size_t o = off; off = (off + bytes + 255) & ~(size_t)255; return o; };
  size_t o_counts = alloc((size_t)N*4);
  size_t o_rp     = alloc((size_t)(N+1)*4);
  size_t o_part   = alloc(1024*4);
  size_t o_cur    = alloc((size_t)N*4);
  size_t o_es     = alloc((size_t)E*8);
  size_t o_M      = alloc((size_t)128*384*2);
  size_t o_wb     = alloc(128*4);
  size_t o_S      = alloc((size_t)N*256*2);
  size_t o_nfb    = alloc((size_t)N*128*2);
  size_t o_flag   = alloc((size_t)N*4);
  size_t need = off;
  bool ws_ok = (ws_size >= need);
  char* base = ws_ok ? (char*)d_ws : (char*)(void*)outE;

  int* counts  = (int*)(base + o_counts);
  int* row_ptr = (int*)(base + o_rp);
  int* partials= (int*)(base + o_part);
  int* cursor  = (int*)(base + o_cur);
  int2* es     = (int2*)(base + o_es);
  unsigned short* Mbf = (unsigned short*)(base + o_M);
  float* Wb    = (float*)(base + o_wb);
  unsigned short* Sbf = (unsigned short*)(base + o_S);
  unsigned short* nfb = (unsigned short*)(base + o_nfb);
  float* flagA = (float*)(base + o_flag);

  hipMemsetAsync(counts, 0, (size_t)N*4, stream);

  int NB = (N + 1023)/1024;
  k_hist   <<<(E+255)/256, 256, 0, stream>>>(dst, counts, E);
  k_scan1  <<<NB, 256, 0, stream>>>(counts, partials, N);
  k_scan2  <<<1, 1024, 0, stream>>>(partials, row_ptr, NB, N);
  k_scan3  <<<NB, 256, 0, stream>>>(counts, partials, row_ptr, cursor, N);
  k_scatter<<<(E+255)/256, 256, 0, stream>>>(src, dst, cursor, es, E);
  k_comb   <<<128, 384, 0, stream>>>(Wa, Wm, bm, Mbf, Wb);
  k_cvt    <<<(N*16 + 255)/256, 256, 0, stream>>>(nf, nfb, N*16);
  k_agg    <<<(N+3)/4, 256, 0, stream>>>(nf, ef, row_ptr, es, Sbf, flagA, N);
  k_gemm   <<<(N+127)/128, 256, 0, stream>>>(nfb, Sbf, Mbf, bap, Wb, flagA, outH, N);
  if (ws_ok)
    k_edge_csr<<<(N+3)/4, 256, 0, stream>>>(outH, row_ptr, es, outE, N);
  else
    k_edge    <<<(E+7)/8, 256, 0, stream>>>(src, dst, outH, outE, E);
}